// Round 4
// baseline (98690.155 us; speedup 1.0000x reference)
//
#include <hip/hip_runtime.h>
#include <cstdint>
#include <cstddef>

// ---------------------------------------------------------------------------
// LSTMModel: embed(mask pad=0) -> LSTM(128->256) -> LSTM(256->256) -> FC(256->64) -> softmax
// B=64 T=2048 D=128 H=256 4H=1024 OUT=64 V=1000
//
// Round 4: r3 counters showed k_lstm = 98% of time, limited by per-CU L2
// weight streaming (512KB/step @ ~134GB/s/CU = 3.8us/step model, 4.25 meas).
// Fix: weights RESIDENT in VGPRs as MFMA A-frags; 4 WGs per batch element
// (64 units x 4 gates = 256 rows = 128KB each), 256 WGs = all CUs; per-step
// h exchange via global + agent-scope flag counters (double-buffered parity);
// XCD swizzle co-locates each batch's 4 WGs (perf-only). MFMA matvec:
// B-frag = h broadcast to all 16 cols, read col 0 of C.
//  - GEMM projections / embed / fc unchanged from r3 (passed, ~2% of time)
//  - chunked over T per ws_size as r3 (CH=1024 observed)
// ---------------------------------------------------------------------------

typedef _Float16 half_t;
typedef _Float16 half8 __attribute__((ext_vector_type(8)));
typedef _Float16 half2t __attribute__((ext_vector_type(2)));
typedef float floatx4 __attribute__((ext_vector_type(4)));

#define B_   64
#define T_   2048
#define D_   128
#define H_   256
#define G4_  1024
#define OUT_ 64
#define MTOT (B_ * T_)

// ---------------- prep kernels ----------------

__global__ __launch_bounds__(256) void k_cvt_f16(const float* __restrict__ in,
                                                 half_t* __restrict__ out, int n) {
  int i = blockIdx.x * 256 + threadIdx.x;
  if (i < n) out[i] = (half_t)in[i];
}

// Whh [1024][256] f32 -> MFMA-A-frag order for k_lstm_mfma:
// wpk[((((w*4+v)*4+m)*8+kt)*64 + l)*8 + e] = Whh[v*256 + w*64 + m*16 + (l&15)][kt*32 + (l>>4)*8 + e]
__global__ __launch_bounds__(256) void k_pack_whh_frag(const float* __restrict__ whh,
                                                       half_t* __restrict__ wpk) {
  int i = blockIdx.x * 256 + threadIdx.x;   // 262144 total
  int e  = i & 7;
  int l  = (i >> 3) & 63;
  int kt = (i >> 9) & 7;
  int m  = (i >> 12) & 3;
  int v  = (i >> 14) & 3;
  int w  = (i >> 16) & 3;
  int row = v * 256 + w * 64 + m * 16 + (l & 15);
  int col = kt * 32 + (l >> 4) * 8 + e;
  wpk[i] = (half_t)whh[row * 256 + col];
}

__global__ __launch_bounds__(256) void k_bias(const float* __restrict__ a,
                                              const float* __restrict__ b,
                                              float* __restrict__ out, int n) {
  int i = blockIdx.x * 256 + threadIdx.x;
  if (i < n) out[i] = a[i] + b[i];
}

// fc_W [64][256] -> fcwt[k*64 + l] = fc_W[l][k]
__global__ __launch_bounds__(256) void k_fcwt(const float* __restrict__ fcw,
                                              float* __restrict__ fcwt) {
  int i = blockIdx.x * 256 + threadIdx.x;   // 16384 total
  fcwt[i] = fcw[(i & 63) * 256 + (i >> 6)];
}

// ---------------- embedding ----------------

__global__ __launch_bounds__(256) void k_embed(const int* __restrict__ x,
                                               const float* __restrict__ tab,
                                               half_t* __restrict__ e) {
  const long i = (long)blockIdx.x * 256 + threadIdx.x;
  const long m = i >> 4;
  const int ch = (int)(i & 15) * 8;
  const int xi = x[m];
  half8 v;
  #pragma unroll
  for (int q = 0; q < 8; ++q) v[q] = (half_t)0.f;
  if (xi != 0) {
    const float* p = tab + (long)xi * D_ + ch;
    #pragma unroll
    for (int q = 0; q < 8; ++q) v[q] = (half_t)p[q];
  }
  *(half8*)(e + m * D_ + ch) = v;
}

// ---------------- f16 MFMA GEMM (unchanged from r3, passed) ----------------
// C[r][N] = A[row(r)][K] @ Wt[N][K]^T + bias ; row(r) = (r>>rowShift)*strideB + toff + (r&mask)

__global__ __launch_bounds__(256) void k_gemm_f16(const half_t* __restrict__ A,
                                                  const half_t* __restrict__ Wt,
                                                  const float* __restrict__ bias,
                                                  half_t* __restrict__ C,
                                                  int K, int N,
                                                  int rowShift, int strideB, int toff) {
  __shared__ half_t As[128][40];
  __shared__ half_t Bs[128][40];
  const int tid  = threadIdx.x;
  const int lane = tid & 63;
  const int wave = tid >> 6;
  const int wr = wave >> 1, wc = wave & 1;
  const int r0 = blockIdx.x * 128;
  const int n0 = blockIdx.y * 128;
  const int srow = tid >> 2;
  const int schunk = (tid & 3) * 8;
  const int rmask = (1 << rowShift) - 1;

  floatx4 zero = {0.f, 0.f, 0.f, 0.f};
  floatx4 acc[4][4];
  for (int i = 0; i < 4; ++i)
    for (int j = 0; j < 4; ++j) acc[i][j] = zero;

  const int ra = r0 + srow, rb = r0 + srow + 64;
  const half_t* ArowA = A + ((long)(ra >> rowShift) * strideB + toff + (ra & rmask)) * K;
  const half_t* ArowB = A + ((long)(rb >> rowShift) * strideB + toff + (rb & rmask)) * K;

  for (int k0 = 0; k0 < K; k0 += 32) {
    *(uint4*)(&As[srow][schunk])      = *(const uint4*)(ArowA + k0 + schunk);
    *(uint4*)(&As[srow + 64][schunk]) = *(const uint4*)(ArowB + k0 + schunk);
    const half_t* Bp = Wt + (long)(n0 + srow) * K + k0 + schunk;
    *(uint4*)(&Bs[srow][schunk])      = *(const uint4*)(Bp);
    *(uint4*)(&Bs[srow + 64][schunk]) = *(const uint4*)(Bp + 64L * K);
    __syncthreads();

    const int kq = (lane >> 4) * 8;
    const int fr = lane & 15;
    half8 af[4], bf[4];
    #pragma unroll
    for (int i = 0; i < 4; ++i) af[i] = *(const half8*)(&As[wr * 64 + i * 16 + fr][kq]);
    #pragma unroll
    for (int i = 0; i < 4; ++i) bf[i] = *(const half8*)(&Bs[wc * 64 + i * 16 + fr][kq]);
    #pragma unroll
    for (int mi = 0; mi < 4; ++mi)
      #pragma unroll
      for (int ni = 0; ni < 4; ++ni)
        acc[mi][ni] = __builtin_amdgcn_mfma_f32_16x16x32_f16(af[mi], bf[ni], acc[mi][ni], 0, 0, 0);
    __syncthreads();
  }

  const int fr = lane & 15, fq = lane >> 4;
  for (int ni = 0; ni < 4; ++ni) {
    const int gcol = n0 + wc * 64 + ni * 16 + fr;
    const float bv = bias[gcol];
    for (int mi = 0; mi < 4; ++mi) {
      const long grow = r0 + wr * 64 + mi * 16 + fq * 4;
      #pragma unroll
      for (int r = 0; r < 4; ++r)
        C[(grow + r) * (long)N + gcol] = (half_t)(acc[mi][ni][r] + bv);
    }
  }
}

// ---------------- LSTM recurrence: 4 WGs per batch, VGPR-resident weights ----------------
// xg [B][steps][1024] f16 (biases included), wpk = frag-packed Whh (512KB),
// hout [B][steps][256] f16, hxch[2][B][256] f16 parity-buffered h exchange,
// flg[B][T_] u32 counters (0 -> 4 per global step), h/c state for chunking.
// Grid: 256 WGs x 256 thr. L=blockIdx: xcd=L&7, k=L>>3, b=xcd*8+(k>>2), w=k&3
// (co-locates batch's 4 WGs on one XCD under round-robin; perf-only).
// Wave v owns gate v (i,f,g,o), units w*64..w*64+63, as 4 row-tiles of 16.

__global__ __launch_bounds__(256, 2) void k_lstm_mfma(const half_t* __restrict__ xg,
                                                      const half_t* __restrict__ wpk,
                                                      half_t* __restrict__ hout,
                                                      half_t* __restrict__ hxch,
                                                      unsigned int* __restrict__ flg,
                                                      half_t* __restrict__ h_state,
                                                      float* __restrict__ c_state,
                                                      int steps, int t0g, int first) {
  const int L = blockIdx.x;
  const int b = (L & 7) * 8 + ((L >> 3) >> 2);
  const int w = (L >> 3) & 3;
  const int r = threadIdx.x;        // 0..255
  const int v = r >> 6;             // wave = gate
  const int l = r & 63;             // lane

  __shared__ half_t hsh[256];
  __shared__ float  gsh[256];
  __shared__ half_t xsh[256];

  // resident A-frags: wreg[m][kt] = rows {v*256 + w*64 + m*16 + (l&15)}, k-slice kt*32+(l>>4)*8
  half8 wreg[4][8];
  {
    const half_t* base = wpk + (size_t)((w * 4 + v) * 4) * 8 * 512;
    #pragma unroll
    for (int m = 0; m < 4; ++m)
      #pragma unroll
      for (int kt = 0; kt < 8; ++kt)
        wreg[m][kt] = *(const half8*)(base + ((m * 8 + kt) * 512 + l * 8));
  }

  const half_t* xgb = xg + (long)b * steps * G4_ + v * 256 + w * 64 + l;
  float c = 0.f;
  if (first) {
    hsh[r] = (half_t)0.f;
  } else {
    hsh[r] = h_state[b * 256 + r];
    if (r < 64) c = c_state[b * 256 + w * 64 + r];
  }
  xsh[r] = xgb[0];
  __syncthreads();

  for (int t = 0; t < steps; ++t) {
    // prefetch next step's xg slice (latency hides under spin+MFMA)
    const int tn = (t + 1 < steps) ? t + 1 : t;
    half_t xnext = xgb[(long)tn * G4_];

    if (t > 0) {
      const unsigned int* fp = &flg[b * T_ + t0g + t - 1];
      while (__hip_atomic_load(fp, __ATOMIC_ACQUIRE, __HIP_MEMORY_SCOPE_AGENT) < 4u)
        __builtin_amdgcn_s_sleep(1);
      hsh[r] = hxch[((t - 1) & 1) * (B_ * 256) + b * 256 + r];
    }
    __syncthreads();                       // B1: hsh ready

    floatx4 acc[4];
    #pragma unroll
    for (int m = 0; m < 4; ++m) acc[m] = (floatx4){0.f, 0.f, 0.f, 0.f};
    #pragma unroll
    for (int kt = 0; kt < 8; ++kt) {
      half8 bq = *(const half8*)(&hsh[kt * 32 + (l >> 4) * 8]);  // broadcast per 16-lane group
      #pragma unroll
      for (int m = 0; m < 4; ++m)
        acc[m] = __builtin_amdgcn_mfma_f32_16x16x32_f16(wreg[m][kt], bq, acc[m], 0, 0, 0);
    }
    // col 0 of C/D: lanes l&15==0; row = m*16 + (l>>4)*4 + reg
    if ((l & 15) == 0) {
      const int q = l >> 4;
      #pragma unroll
      for (int m = 0; m < 4; ++m)
        #pragma unroll
        for (int reg = 0; reg < 4; ++reg)
          gsh[v * 64 + m * 16 + q * 4 + reg] = acc[m][reg];
    }
    __syncthreads();                       // B2: gsh ready

    float gi = 0.f, gf = 0.f, gg = 0.f, go = 0.f;
    if (r < 64) {
      gi = gsh[r]       + (float)xsh[r];
      gf = gsh[64 + r]  + (float)xsh[64 + r];
      gg = gsh[128 + r] + (float)xsh[128 + r];
      go = gsh[192 + r] + (float)xsh[192 + r];
    }
    __syncthreads();                       // B3: xsh reads done
    xsh[r] = xnext;
    if (r < 64) {
      float ig = 1.f / (1.f + __expf(-gi));
      float fg = 1.f / (1.f + __expf(-gf));
      float g2 = tanhf(gg);
      float og = 1.f / (1.f + __expf(-go));
      c = fg * c + ig * g2;
      float h = og * tanhf(c);
      half_t hh = (half_t)h;
      hout[(long)b * steps * H_ + (long)t * H_ + w * 64 + r] = hh;
      hxch[(t & 1) * (B_ * 256) + b * 256 + w * 64 + r] = hh;
      if (t == steps - 1) {
        h_state[b * 256 + w * 64 + r] = hh;
        c_state[b * 256 + w * 64 + r] = c;
      }
    }
    __syncthreads();                       // B4: h stores complete WG-wide
    if (r == 0) {
      __threadfence();                     // agent visibility of WG's h stores
      __hip_atomic_fetch_add(&flg[b * T_ + t0g + t], 1u,
                             __ATOMIC_RELEASE, __HIP_MEMORY_SCOPE_AGENT);
    }
  }
}

// ---------------- FC + softmax (unchanged from r3) ----------------

__global__ __launch_bounds__(256) void k_fc_softmax(const half_t* __restrict__ h2,
                                                    const float* __restrict__ fcwt,
                                                    const float* __restrict__ fcb,
                                                    float* __restrict__ out,
                                                    int rowShift, int strideB, int toff) {
  const int lane = threadIdx.x & 63;
  const int r = blockIdx.x * 4 + (threadIdx.x >> 6);
  const half_t* hr = h2 + (long)r * H_;
  float acc = fcb[lane];
  for (int kc = 0; kc < 32; ++kc) {
    uint4 hv = *(const uint4*)(hr + kc * 8);
    unsigned hu[4] = {hv.x, hv.y, hv.z, hv.w};
    #pragma unroll
    for (int p = 0; p < 4; ++p) {
      half2t hh = __builtin_bit_cast(half2t, hu[p]);
      acc += (float)hh[0] * fcwt[(kc * 8 + p * 2) * 64 + lane];
      acc += (float)hh[1] * fcwt[(kc * 8 + p * 2 + 1) * 64 + lane];
    }
  }
  float m = acc;
  #pragma unroll
  for (int off = 32; off > 0; off >>= 1) m = fmaxf(m, __shfl_xor(m, off));
  float e = __expf(acc - m);
  float s = e;
  #pragma unroll
  for (int off = 32; off > 0; off >>= 1) s += __shfl_xor(s, off);
  const long outrow = (long)(r >> rowShift) * strideB + toff + (r & ((1 << rowShift) - 1));
  out[outrow * OUT_ + lane] = e / s;
}

// ---------------- launch ----------------

extern "C" void kernel_launch(void* const* d_in, const int* in_sizes, int n_in,
                              void* d_out, int out_size, void* d_ws, size_t ws_size,
                              hipStream_t stream) {
  const int*   x    = (const int*)d_in[0];
  const float* tab  = (const float*)d_in[1];
  const float* wih0 = (const float*)d_in[2];
  const float* whh0 = (const float*)d_in[3];
  const float* bih0 = (const float*)d_in[4];
  const float* bhh0 = (const float*)d_in[5];
  const float* wih1 = (const float*)d_in[6];
  const float* whh1 = (const float*)d_in[7];
  const float* bih1 = (const float*)d_in[8];
  const float* bhh1 = (const float*)d_in[9];
  const float* fcw  = (const float*)d_in[10];
  const float* fcb  = (const float*)d_in[11];

  char* p = (char*)d_ws;
  auto alloc = [&](size_t bytes) {
    void* r = (void*)p;
    p += (bytes + 255) & ~(size_t)255;
    return r;
  };
  half_t* wih0_h = (half_t*)alloc((size_t)G4_ * D_ * 2);
  half_t* wih1_h = (half_t*)alloc((size_t)G4_ * H_ * 2);
  half_t* wpk0   = (half_t*)alloc((size_t)G4_ * H_ * 2);   // frag-packed Whh0
  half_t* wpk1   = (half_t*)alloc((size_t)G4_ * H_ * 2);   // frag-packed Whh1
  float*  bias0  = (float*)alloc(G4_ * 4);
  float*  bias1  = (float*)alloc(G4_ * 4);
  float*  fcwt   = (float*)alloc((size_t)H_ * OUT_ * 4);
  half_t* hstate = (half_t*)alloc((size_t)2 * B_ * H_ * 2);
  float*  cstate = (float*)alloc((size_t)2 * B_ * H_ * 4);
  half_t* hxch   = (half_t*)alloc((size_t)2 * B_ * H_ * 2);          // parity-buffered h
  unsigned int* flg = (unsigned int*)alloc((size_t)2 * B_ * T_ * 4); // 1MB counters
  size_t fixed_used = (size_t)(p - (char*)d_ws);

  // Chunk length: largest power-of-2 CH <= 2048 with XG+HB fitting in ws.
  int CH = 2048;
  while (CH > 32 &&
         fixed_used + (size_t)CH * (131072 + 32768) + (4u << 20) > ws_size)
    CH >>= 1;
  const int rowShift = __builtin_ctz(CH);
  half_t* XG = (half_t*)alloc((size_t)CH * B_ * G4_ * 2);
  half_t* HB = (half_t*)alloc((size_t)CH * B_ * H_ * 2);
  half_t* ebuf = (half_t*)d_out;   // 32MB == out bytes; rows consumed before FC writes

  // prep (tiny)
  k_cvt_f16<<<512, 256, 0, stream>>>(wih0, wih0_h, G4_ * D_);
  k_cvt_f16<<<1024, 256, 0, stream>>>(wih1, wih1_h, G4_ * H_);
  k_pack_whh_frag<<<1024, 256, 0, stream>>>(whh0, wpk0);
  k_pack_whh_frag<<<1024, 256, 0, stream>>>(whh1, wpk1);
  k_bias<<<4, 256, 0, stream>>>(bih0, bhh0, bias0, G4_);
  k_bias<<<4, 256, 0, stream>>>(bih1, bhh1, bias1, G4_);
  k_fcwt<<<64, 256, 0, stream>>>(fcw, fcwt);
  hipMemsetAsync(flg, 0, (size_t)2 * B_ * T_ * 4, stream);  // ws is 0xAA-poisoned

  k_embed<<<MTOT * (D_ / 8) / 256, 256, 0, stream>>>(x, tab, ebuf);

  const int M = B_ * CH;
  const int nchunks = T_ / CH;
  for (int ci = 0; ci < nchunks; ++ci) {
    const int t0 = ci * CH;
    // layer-0 projection: e (strided rows in d_out) -> XG
    k_gemm_f16<<<dim3(M / 128, G4_ / 128), 256, 0, stream>>>(
        ebuf, wih0_h, bias0, XG, D_, G4_, rowShift, T_, t0);
    // layer-0 recurrence
    k_lstm_mfma<<<256, 256, 0, stream>>>(XG, wpk0, HB, hxch, flg,
                                         hstate, cstate, CH, t0, ci == 0);
    // layer-1 projection: HB -> XG (reuse)
    k_gemm_f16<<<dim3(M / 128, G4_ / 128), 256, 0, stream>>>(
        HB, wih1_h, bias1, XG, H_, G4_, rowShift, CH, 0);
    // layer-1 recurrence
    k_lstm_mfma<<<256, 256, 0, stream>>>(XG, wpk1, HB, hxch, flg + B_ * T_,
                                         hstate + B_ * H_, cstate + B_ * H_, CH, t0, ci == 0);
    // FC + softmax: HB -> out rows (b*T + t0 + t')
    k_fc_softmax<<<M / 4, 256, 0, stream>>>(HB, fcwt, fcb, (float*)d_out,
                                            rowShift, T_, t0);
  }
}

// Round 5
// 7634.769 us; speedup vs baseline: 12.9264x; 12.9264x over previous
//
#include <hip/hip_runtime.h>
#include <cstdint>
#include <cstddef>

// ---------------------------------------------------------------------------
// LSTMModel: embed(mask pad=0) -> LSTM(128->256) -> LSTM(256->256) -> FC(256->64) -> softmax
// B=64 T=2048 D=128 H=256 4H=1024 OUT=64 V=1000
//
// Round 5: r4's cross-WG flag sync cost 23.6us/step (coherent-point round
// trips) -> abandoned. Back to r3's proven single-WG-per-batch recurrence,
// but with Whh fully RESIDENT per CU: row j split 200 elems in VGPRs
// (25 uint4 = 100 regs) + 56 elems in LDS ([7][1024] uint4 chunk-major,
// 112KB dynamic, conflict-free). Removes r3's 512KB/step L2 stream
// (3.8us/step). New floor: 128 v_dot2/thread = ~1024 cyc VALU/step.
// Fallback: if 112KB dynamic-LDS attr fails, launch r3 streaming kernel.
//  - GEMM/embed/fc/chunking unchanged from r3 (passed, ~250us total)
// ---------------------------------------------------------------------------

typedef _Float16 half_t;
typedef _Float16 half8 __attribute__((ext_vector_type(8)));
typedef _Float16 half2t __attribute__((ext_vector_type(2)));
typedef float floatx4 __attribute__((ext_vector_type(4)));

#define B_   64
#define T_   2048
#define D_   128
#define H_   256
#define G4_  1024
#define OUT_ 64
#define MTOT (B_ * T_)

#define EVC  25                    // VGPR-resident uint4 chunks per row (200 elems)
#define TLC  7                     // LDS-resident tail chunks per row (56 elems)
#define TL_BYTES (TLC * 1024 * 16) // 112 KB dynamic LDS

#if defined(__has_builtin)
#if __has_builtin(__builtin_amdgcn_fdot2)
#define HAVE_FDOT2 1
#endif
#endif

__device__ __forceinline__ float dot2acc(unsigned w, unsigned h, float acc) {
  half2t a = __builtin_bit_cast(half2t, w);
  half2t b = __builtin_bit_cast(half2t, h);
#ifdef HAVE_FDOT2
  return __builtin_amdgcn_fdot2(a, b, acc, false);
#else
  return acc + (float)a[0] * (float)b[0] + (float)a[1] * (float)b[1];
#endif
}

__device__ __forceinline__ float fast_sigmoid(float x) {
  return 1.f / (1.f + __expf(-x));
}
__device__ __forceinline__ float fast_tanh(float x) {
  return 1.f - 2.f / (1.f + __expf(2.f * x));
}

// ---------------- prep kernels ----------------

__global__ __launch_bounds__(256) void k_cvt_f16(const float* __restrict__ in,
                                                 half_t* __restrict__ out, int n) {
  int i = blockIdx.x * 256 + threadIdx.x;
  if (i < n) out[i] = (half_t)in[i];
}

// Whh [1024][256] f32 -> wp[(kc*1024 + j)*8 + e] = Whh[j][kc*8+e]  (f16)
__global__ __launch_bounds__(256) void k_pack_whh(const float* __restrict__ whh,
                                                  half_t* __restrict__ wp) {
  int i = blockIdx.x * 256 + threadIdx.x;      // 262144 total
  int e  = i & 7;
  int j  = (i >> 3) & 1023;
  int kc = i >> 13;
  wp[i] = (half_t)whh[j * 256 + kc * 8 + e];
}

__global__ __launch_bounds__(256) void k_bias(const float* __restrict__ a,
                                              const float* __restrict__ b,
                                              float* __restrict__ out, int n) {
  int i = blockIdx.x * 256 + threadIdx.x;
  if (i < n) out[i] = a[i] + b[i];
}

// fc_W [64][256] -> fcwt[k*64 + l] = fc_W[l][k]
__global__ __launch_bounds__(256) void k_fcwt(const float* __restrict__ fcw,
                                              float* __restrict__ fcwt) {
  int i = blockIdx.x * 256 + threadIdx.x;      // 16384 total
  fcwt[i] = fcw[(i & 63) * 256 + (i >> 6)];
}

// ---------------- embedding ----------------

__global__ __launch_bounds__(256) void k_embed(const int* __restrict__ x,
                                               const float* __restrict__ tab,
                                               half_t* __restrict__ e) {
  const long i = (long)blockIdx.x * 256 + threadIdx.x;
  const long m = i >> 4;
  const int ch = (int)(i & 15) * 8;
  const int xi = x[m];
  half8 v;
  #pragma unroll
  for (int q = 0; q < 8; ++q) v[q] = (half_t)0.f;
  if (xi != 0) {
    const float* p = tab + (long)xi * D_ + ch;
    #pragma unroll
    for (int q = 0; q < 8; ++q) v[q] = (half_t)p[q];
  }
  *(half8*)(e + m * D_ + ch) = v;
}

// ---------------- f16 MFMA GEMM (unchanged from r3, passed) ----------------

__global__ __launch_bounds__(256) void k_gemm_f16(const half_t* __restrict__ A,
                                                  const half_t* __restrict__ Wt,
                                                  const float* __restrict__ bias,
                                                  half_t* __restrict__ C,
                                                  int K, int N,
                                                  int rowShift, int strideB, int toff) {
  __shared__ half_t As[128][40];
  __shared__ half_t Bs[128][40];
  const int tid  = threadIdx.x;
  const int lane = tid & 63;
  const int wave = tid >> 6;
  const int wr = wave >> 1, wc = wave & 1;
  const int r0 = blockIdx.x * 128;
  const int n0 = blockIdx.y * 128;
  const int srow = tid >> 2;
  const int schunk = (tid & 3) * 8;
  const int rmask = (1 << rowShift) - 1;

  floatx4 zero = {0.f, 0.f, 0.f, 0.f};
  floatx4 acc[4][4];
  for (int i = 0; i < 4; ++i)
    for (int j = 0; j < 4; ++j) acc[i][j] = zero;

  const int ra = r0 + srow, rb = r0 + srow + 64;
  const half_t* ArowA = A + ((long)(ra >> rowShift) * strideB + toff + (ra & rmask)) * K;
  const half_t* ArowB = A + ((long)(rb >> rowShift) * strideB + toff + (rb & rmask)) * K;

  for (int k0 = 0; k0 < K; k0 += 32) {
    *(uint4*)(&As[srow][schunk])      = *(const uint4*)(ArowA + k0 + schunk);
    *(uint4*)(&As[srow + 64][schunk]) = *(const uint4*)(ArowB + k0 + schunk);
    const half_t* Bp = Wt + (long)(n0 + srow) * K + k0 + schunk;
    *(uint4*)(&Bs[srow][schunk])      = *(const uint4*)(Bp);
    *(uint4*)(&Bs[srow + 64][schunk]) = *(const uint4*)(Bp + 64L * K);
    __syncthreads();

    const int kq = (lane >> 4) * 8;
    const int fr = lane & 15;
    half8 af[4], bf[4];
    #pragma unroll
    for (int i = 0; i < 4; ++i) af[i] = *(const half8*)(&As[wr * 64 + i * 16 + fr][kq]);
    #pragma unroll
    for (int i = 0; i < 4; ++i) bf[i] = *(const half8*)(&Bs[wc * 64 + i * 16 + fr][kq]);
    #pragma unroll
    for (int mi = 0; mi < 4; ++mi)
      #pragma unroll
      for (int ni = 0; ni < 4; ++ni)
        acc[mi][ni] = __builtin_amdgcn_mfma_f32_16x16x32_f16(af[mi], bf[ni], acc[mi][ni], 0, 0, 0);
    __syncthreads();
  }

  const int fr = lane & 15, fq = lane >> 4;
  for (int ni = 0; ni < 4; ++ni) {
    const int gcol = n0 + wc * 64 + ni * 16 + fr;
    const float bv = bias[gcol];
    for (int mi = 0; mi < 4; ++mi) {
      const long grow = r0 + wr * 64 + mi * 16 + fq * 4;
      #pragma unroll
      for (int r = 0; r < 4; ++r)
        C[(grow + r) * (long)N + gcol] = (half_t)(acc[mi][ni][r] + bv);
    }
  }
}

// ---------------- LSTM recurrence: weights resident (VGPR + LDS) ----------------
// One WG (1024 thr) per batch. Thread j owns gate row j: chunks 0..24 in VGPRs,
// chunks 25..31 in dynamic LDS [c][1024] uint4 (conflict-free). No cross-WG sync.

__global__ __launch_bounds__(1024) void k_lstm_res(const half_t* __restrict__ xg,
                                                   const uint4* __restrict__ Wp,
                                                   half_t* __restrict__ hout,
                                                   float* __restrict__ c_state,
                                                   half_t* __restrict__ h_state,
                                                   int steps, int first) {
  extern __shared__ uint4 wtail[];            // [TLC][1024]
  __shared__ float gsh[1024];
  __shared__ __align__(16) half_t hsh[256];
  const int b = blockIdx.x;
  const int j = threadIdx.x;

  // one-time: resident weights (row j) -> VGPRs, tail -> LDS (both coalesced)
  uint4 wv[EVC];
  #pragma unroll
  for (int kc = 0; kc < EVC; ++kc) wv[kc] = Wp[kc * 1024 + j];
  #pragma unroll
  for (int cc = 0; cc < TLC; ++cc) wtail[cc * 1024 + j] = Wp[(EVC + cc) * 1024 + j];

  float c = 0.f;
  if (j < H_) {
    if (first) {
      hsh[j] = (half_t)0.f;
    } else {
      hsh[j] = h_state[b * H_ + j];
      c = c_state[b * H_ + j];
    }
  }

  const half_t* xp = xg + (long)b * steps * G4_ + j;
  half_t* hp_out = hout + (long)b * steps * H_;
  half_t xv = xp[0];

  for (int t = 0; t < steps; ++t) {
    const int tn = (t + 1 < steps) ? t + 1 : t;
    half_t xnext = xp[(long)tn * G4_];        // prefetch, hides under dots
    __syncthreads();                          // hsh(t-1) ready
    float acc = (float)xv;
    const uint4* hv4 = (const uint4*)hsh;
    #pragma unroll
    for (int kc = 0; kc < EVC; ++kc) {        // VGPR-resident part (k = 0..199)
      uint4 w = wv[kc];
      uint4 h4 = hv4[kc];                     // LDS broadcast
      acc = dot2acc(w.x, h4.x, acc);
      acc = dot2acc(w.y, h4.y, acc);
      acc = dot2acc(w.z, h4.z, acc);
      acc = dot2acc(w.w, h4.w, acc);
    }
    #pragma unroll
    for (int cc = 0; cc < TLC; ++cc) {        // LDS-resident tail (k = 200..255)
      uint4 w = wtail[cc * 1024 + j];
      uint4 h4 = hv4[EVC + cc];
      acc = dot2acc(w.x, h4.x, acc);
      acc = dot2acc(w.y, h4.y, acc);
      acc = dot2acc(w.z, h4.z, acc);
      acc = dot2acc(w.w, h4.w, acc);
    }
    gsh[j] = acc;
    xv = xnext;
    __syncthreads();                          // gsh ready (and hsh reads done)
    if (j < H_) {
      float ig = fast_sigmoid(gsh[j]);
      float fg = fast_sigmoid(gsh[H_ + j]);
      float g2 = fast_tanh(gsh[2 * H_ + j]);
      float og = fast_sigmoid(gsh[3 * H_ + j]);
      c = fg * c + ig * g2;
      float h = og * fast_tanh(c);
      half_t hh = (half_t)h;
      hp_out[(long)t * H_ + j] = hh;
      hsh[j] = hh;                            // race-free: readers wait at top barrier
    }
  }
  if (j < H_) {
    c_state[b * H_ + j] = c;
    h_state[b * H_ + j] = hsh[j];
  }
}

// ---------------- r3 streaming recurrence (fallback if big-LDS attr fails) ----------------

__global__ __launch_bounds__(1024) void k_lstm(const half_t* __restrict__ xg,
                                               const uint4* __restrict__ Wp,
                                               half_t* __restrict__ hout,
                                               float* __restrict__ c_state,
                                               half_t* __restrict__ h_state,
                                               int steps, int first) {
  const int b = blockIdx.x;
  const int j = threadIdx.x;
  __shared__ float gsh[1024];
  __shared__ __align__(16) half_t hsh[256];
  float c = 0.f;
  if (j < H_) {
    if (first) {
      hsh[j] = (half_t)0.f;
    } else {
      hsh[j] = h_state[b * H_ + j];
      c = c_state[b * H_ + j];
    }
  }
  const uint4*  wp     = Wp + j;
  const half_t* xp     = xg + (long)b * steps * G4_ + j;
  half_t*       hp_out = hout + (long)b * steps * H_;
  for (int t = 0; t < steps; ++t) {
    __syncthreads();
    float acc = (float)xp[(long)t * G4_];
    const uint4* hv4 = (const uint4*)hsh;
    #pragma unroll 8
    for (int kc = 0; kc < 32; ++kc) {
      uint4 w  = wp[(long)kc * G4_];
      uint4 h4 = hv4[kc];
      acc = dot2acc(w.x, h4.x, acc);
      acc = dot2acc(w.y, h4.y, acc);
      acc = dot2acc(w.z, h4.z, acc);
      acc = dot2acc(w.w, h4.w, acc);
    }
    gsh[j] = acc;
    __syncthreads();
    if (j < H_) {
      float ig = fast_sigmoid(gsh[j]);
      float fg = fast_sigmoid(gsh[H_ + j]);
      float g2 = fast_tanh(gsh[2 * H_ + j]);
      float og = fast_sigmoid(gsh[3 * H_ + j]);
      c = fg * c + ig * g2;
      float h = og * fast_tanh(c);
      hp_out[(long)t * H_ + j] = (half_t)h;
      hsh[j] = (half_t)h;
    }
  }
  if (j < H_) {
    c_state[b * H_ + j] = c;
    h_state[b * H_ + j] = hsh[j];
  }
}

// ---------------- FC + softmax (unchanged from r3) ----------------

__global__ __launch_bounds__(256) void k_fc_softmax(const half_t* __restrict__ h2,
                                                    const float* __restrict__ fcwt,
                                                    const float* __restrict__ fcb,
                                                    float* __restrict__ out,
                                                    int rowShift, int strideB, int toff) {
  const int lane = threadIdx.x & 63;
  const int r = blockIdx.x * 4 + (threadIdx.x >> 6);
  const half_t* hr = h2 + (long)r * H_;
  float acc = fcb[lane];
  for (int kc = 0; kc < 32; ++kc) {
    uint4 hv = *(const uint4*)(hr + kc * 8);
    unsigned hu[4] = {hv.x, hv.y, hv.z, hv.w};
    #pragma unroll
    for (int p = 0; p < 4; ++p) {
      half2t hh = __builtin_bit_cast(half2t, hu[p]);
      acc += (float)hh[0] * fcwt[(kc * 8 + p * 2) * 64 + lane];
      acc += (float)hh[1] * fcwt[(kc * 8 + p * 2 + 1) * 64 + lane];
    }
  }
  float m = acc;
  #pragma unroll
  for (int off = 32; off > 0; off >>= 1) m = fmaxf(m, __shfl_xor(m, off));
  float e = __expf(acc - m);
  float s = e;
  #pragma unroll
  for (int off = 32; off > 0; off >>= 1) s += __shfl_xor(s, off);
  const long outrow = (long)(r >> rowShift) * strideB + toff + (r & ((1 << rowShift) - 1));
  out[outrow * OUT_ + lane] = e / s;
}

// ---------------- launch ----------------

extern "C" void kernel_launch(void* const* d_in, const int* in_sizes, int n_in,
                              void* d_out, int out_size, void* d_ws, size_t ws_size,
                              hipStream_t stream) {
  const int*   x    = (const int*)d_in[0];
  const float* tab  = (const float*)d_in[1];
  const float* wih0 = (const float*)d_in[2];
  const float* whh0 = (const float*)d_in[3];
  const float* bih0 = (const float*)d_in[4];
  const float* bhh0 = (const float*)d_in[5];
  const float* wih1 = (const float*)d_in[6];
  const float* whh1 = (const float*)d_in[7];
  const float* bih1 = (const float*)d_in[8];
  const float* bhh1 = (const float*)d_in[9];
  const float* fcw  = (const float*)d_in[10];
  const float* fcb  = (const float*)d_in[11];

  char* p = (char*)d_ws;
  auto alloc = [&](size_t bytes) {
    void* r = (void*)p;
    p += (bytes + 255) & ~(size_t)255;
    return r;
  };
  half_t* wih0_h = (half_t*)alloc((size_t)G4_ * D_ * 2);
  half_t* wih1_h = (half_t*)alloc((size_t)G4_ * H_ * 2);
  half_t* wp0    = (half_t*)alloc((size_t)G4_ * H_ * 2);
  half_t* wp1    = (half_t*)alloc((size_t)G4_ * H_ * 2);
  float*  bias0  = (float*)alloc(G4_ * 4);
  float*  bias1  = (float*)alloc(G4_ * 4);
  float*  fcwt   = (float*)alloc((size_t)H_ * OUT_ * 4);
  half_t* hstate = (half_t*)alloc((size_t)2 * B_ * H_ * 2);
  float*  cstate = (float*)alloc((size_t)2 * B_ * H_ * 4);
  size_t fixed_used = (size_t)(p - (char*)d_ws);

  // Chunk length: largest power-of-2 CH <= 2048 with XG+HB fitting in ws.
  int CH = 2048;
  while (CH > 32 &&
         fixed_used + (size_t)CH * (131072 + 32768) + (1u << 20) > ws_size)
    CH >>= 1;
  const int rowShift = __builtin_ctz(CH);
  half_t* XG = (half_t*)alloc((size_t)CH * B_ * G4_ * 2);
  half_t* HB = (half_t*)alloc((size_t)CH * B_ * H_ * 2);
  half_t* ebuf = (half_t*)d_out;   // 32MB == out bytes; rows consumed before FC writes

  // big dynamic LDS for resident recurrence; deterministic fallback if denied
  hipError_t attr_rc = hipFuncSetAttribute(
      reinterpret_cast<const void*>(k_lstm_res),
      hipFuncAttributeMaxDynamicSharedMemorySize, TL_BYTES);
  const bool use_res = (attr_rc == hipSuccess);

  // prep (tiny)
  k_cvt_f16<<<512, 256, 0, stream>>>(wih0, wih0_h, G4_ * D_);
  k_cvt_f16<<<1024, 256, 0, stream>>>(wih1, wih1_h, G4_ * H_);
  k_pack_whh<<<1024, 256, 0, stream>>>(whh0, wp0);
  k_pack_whh<<<1024, 256, 0, stream>>>(whh1, wp1);
  k_bias<<<4, 256, 0, stream>>>(bih0, bhh0, bias0, G4_);
  k_bias<<<4, 256, 0, stream>>>(bih1, bhh1, bias1, G4_);
  k_fcwt<<<64, 256, 0, stream>>>(fcw, fcwt);

  k_embed<<<MTOT * (D_ / 8) / 256, 256, 0, stream>>>(x, tab, ebuf);

  const int M = B_ * CH;
  const int nchunks = T_ / CH;
  for (int ci = 0; ci < nchunks; ++ci) {
    const int t0 = ci * CH;
    k_gemm_f16<<<dim3(M / 128, G4_ / 128), 256, 0, stream>>>(
        ebuf, wih0_h, bias0, XG, D_, G4_, rowShift, T_, t0);
    if (use_res)
      k_lstm_res<<<B_, 1024, TL_BYTES, stream>>>(XG, (const uint4*)wp0, HB,
                                                 cstate, hstate, CH, ci == 0);
    else
      k_lstm<<<B_, 1024, 0, stream>>>(XG, (const uint4*)wp0, HB,
                                      cstate, hstate, CH, ci == 0);
    k_gemm_f16<<<dim3(M / 128, G4_ / 128), 256, 0, stream>>>(
        HB, wih1_h, bias1, XG, H_, G4_, rowShift, CH, 0);
    if (use_res)
      k_lstm_res<<<B_, 1024, TL_BYTES, stream>>>(XG, (const uint4*)wp1, HB,
                                                 cstate + B_ * H_, hstate + B_ * H_,
                                                 CH, ci == 0);
    else
      k_lstm<<<B_, 1024, 0, stream>>>(XG, (const uint4*)wp1, HB,
                                      cstate + B_ * H_, hstate + B_ * H_,
                                      CH, ci == 0);
    k_fc_softmax<<<M / 4, 256, 0, stream>>>(HB, fcwt, fcb, (float*)d_out,
                                            rowShift, T_, t0);
  }
}